// Round 5
// baseline (34.090 us; speedup 1.0000x reference)
//
#include <hip/hip_runtime.h>

// Resize [B,D,H,W,C=2] fp32, zoom 1.5/axis, neurite linear conv (edge clip).
// Per axis: out[3k]=in[2k], out[3k+1]=(in[2k]+2 in[2k+1])/3, out[3k+2]=(2 in[2k+1]+in[2k+2])/3.
// One thread = 1(z) x 3(y) x 3(x) output tile; weights are literals {1,1/3,2/3}.
// Stores are non-temporal: output is write-once streaming (73% of HBM traffic),
// keep it out of L2 so the input's reuse window stays resident.
constexpr int B = 2, D = 128, H = 128, W = 128;
constexpr int OD = 192, OH = 192, OW = 192;

typedef float v4f __attribute__((ext_vector_type(4), aligned(8)));
typedef float v2f __attribute__((ext_vector_type(2), aligned(8)));

__device__ __forceinline__ float2 lerp13(float2 u, float2 v) {   // (u + 2v)/3
    constexpr float A = 1.0f / 3.0f, Bc = 2.0f / 3.0f;
    return float2{A * u.x + Bc * v.x, A * u.y + Bc * v.y};
}
__device__ __forceinline__ float2 lerp23(float2 u, float2 v) {   // (2u + v)/3
    constexpr float A = 1.0f / 3.0f, Bc = 2.0f / 3.0f;
    return float2{Bc * u.x + A * v.x, Bc * u.y + A * v.y};
}

__device__ __forceinline__ void nt_store_row(float2* __restrict__ o,
                                             float2 a, float2 b, float2 c) {
    v4f p4 = {a.x, a.y, b.x, b.y};
    v2f p2 = {c.x, c.y};
    __builtin_nontemporal_store(p4, (v4f*)o);
    __builtin_nontemporal_store(p2, (v2f*)(o + 2));
}

__global__ __launch_bounds__(256, 6)
void resize9nt(const float2* __restrict__ in, float2* __restrict__ out) {
    const int X = threadIdx.x;                    // 0..63 x-triple
    const int Y = blockIdx.x * 4 + threadIdx.y;   // 0..63 y-triple
    const int z = blockIdx.y;                     // 0..191 output z (block-uniform)
    const int b = blockIdx.z;

    const int k = z / 3, r = z - 3 * k;           // block-uniform (scalar)
    const int ix = 2 * X, iy = 2 * Y;
    const int xc = (ix + 2 < W) ? ix + 2 : W - 1;
    const int yc = (iy + 2 < H) ? iy + 2 : H - 1;

    const float2* base = in + (size_t)b * (D * H * W);

    float2 m[3][3];                               // z-merged 3x3 (y,x) patch
    if (r == 0) {
        const float2* p = base + (size_t)(2 * k) * (H * W);
        const float2* r0 = p + (size_t)iy * W;
        const float2* r1 = r0 + W;
        const float2* r2 = p + (size_t)yc * W;
        m[0][0] = r0[ix]; m[0][1] = r0[ix + 1]; m[0][2] = r0[xc];
        m[1][0] = r1[ix]; m[1][1] = r1[ix + 1]; m[1][2] = r1[xc];
        m[2][0] = r2[ix]; m[2][1] = r2[ix + 1]; m[2][2] = r2[xc];
    } else {
        const int izA = (r == 1) ? 2 * k : 2 * k + 1;
        const int izB = (izA + 1 < D) ? izA + 1 : D - 1;
        const float wA = (r == 1) ? (1.0f / 3.0f) : (2.0f / 3.0f);
        const float wB = (r == 1) ? (2.0f / 3.0f) : (1.0f / 3.0f);
        const float2* pA = base + (size_t)izA * (H * W);
        const float2* pB = base + (size_t)izB * (H * W);
        const float2* a0 = pA + (size_t)iy * W;
        const float2* a1 = a0 + W;
        const float2* a2 = pA + (size_t)yc * W;
        const float2* b0 = pB + (size_t)iy * W;
        const float2* b1 = b0 + W;
        const float2* b2 = pB + (size_t)yc * W;
        float2 a[3][3], bb[3][3];
        a[0][0] = a0[ix]; a[0][1] = a0[ix + 1]; a[0][2] = a0[xc];
        a[1][0] = a1[ix]; a[1][1] = a1[ix + 1]; a[1][2] = a1[xc];
        a[2][0] = a2[ix]; a[2][1] = a2[ix + 1]; a[2][2] = a2[xc];
        bb[0][0] = b0[ix]; bb[0][1] = b0[ix + 1]; bb[0][2] = b0[xc];
        bb[1][0] = b1[ix]; bb[1][1] = b1[ix + 1]; bb[1][2] = b1[xc];
        bb[2][0] = b2[ix]; bb[2][1] = b2[ix + 1]; bb[2][2] = b2[xc];
#pragma unroll
        for (int i = 0; i < 3; ++i)
#pragma unroll
            for (int j = 0; j < 3; ++j) {
                m[i][j].x = wA * a[i][j].x + wB * bb[i][j].x;
                m[i][j].y = wA * a[i][j].y + wB * bb[i][j].y;
            }
    }

    // x-interp each row, then y-interp -> 3 output rows of 24 B/lane
    float2 t0[3], t1[3], t2[3];
    t0[0] = m[0][0]; t0[1] = lerp13(m[0][0], m[0][1]); t0[2] = lerp23(m[0][1], m[0][2]);
    t1[0] = m[1][0]; t1[1] = lerp13(m[1][0], m[1][1]); t1[2] = lerp23(m[1][1], m[1][2]);
    t2[0] = m[2][0]; t2[1] = lerp13(m[2][0], m[2][1]); t2[2] = lerp23(m[2][1], m[2][2]);

    float2* o0 = out + (((size_t)b * OD + z) * OH + 3 * Y) * OW + 3 * X;
    float2* o1 = o0 + OW;
    float2* o2 = o0 + 2 * OW;
    nt_store_row(o0, t0[0], t0[1], t0[2]);
    nt_store_row(o1, lerp13(t0[0], t1[0]), lerp13(t0[1], t1[1]), lerp13(t0[2], t1[2]));
    nt_store_row(o2, lerp23(t1[0], t2[0]), lerp23(t1[1], t2[1]), lerp23(t1[2], t2[2]));
}

extern "C" void kernel_launch(void* const* d_in, const int* in_sizes, int n_in,
                              void* d_out, int out_size, void* d_ws, size_t ws_size,
                              hipStream_t stream) {
    const float2* in = (const float2*)d_in[0];
    float2* out = (float2*)d_out;
    dim3 block(64, 4, 1);
    dim3 grid(16, OD, B);    // (y-triple groups, output z, batch)
    resize9nt<<<grid, block, 0, stream>>>(in, out);
}

// Round 6
// 28.285 us; speedup vs baseline: 1.2052x; 1.2052x over previous
//
#include <hip/hip_runtime.h>

// Resize [B,D,H,W,C=2] fp32, zoom 1.5/axis, neurite linear conv (edge clip).
// Per axis: out[3k]=in[2k], out[3k+1]=(in[2k]+2 in[2k+1])/3, out[3k+2]=(2 in[2k+1]+in[2k+2])/3.
// One thread = 1(z) x 3(y) x 3(x) output tile; weights are literals {1,1/3,2/3}.
// Loads: row[2X],row[2X+1] merged into one 16B-aligned float4 + one 8B load for row[xc].
constexpr int B = 2, D = 128, H = 128, W = 128;
constexpr int OD = 192, OH = 192, OW = 192;

__device__ __forceinline__ float2 lerp13(float2 u, float2 v) {   // (u + 2v)/3
    constexpr float A = 1.0f / 3.0f, Bc = 2.0f / 3.0f;
    return float2{A * u.x + Bc * v.x, A * u.y + Bc * v.y};
}
__device__ __forceinline__ float2 lerp23(float2 u, float2 v) {   // (2u + v)/3
    constexpr float A = 1.0f / 3.0f, Bc = 2.0f / 3.0f;
    return float2{Bc * u.x + A * v.x, Bc * u.y + A * v.y};
}

__device__ __forceinline__ void load_row3(const float2* __restrict__ row,
                                          int ix, int xc, float2 out3[3]) {
    float4 q = *reinterpret_cast<const float4*>(row + ix);   // 16B aligned (ix even)
    out3[0] = float2{q.x, q.y};
    out3[1] = float2{q.z, q.w};
    out3[2] = row[xc];
}

__global__ __launch_bounds__(256)
void resize9v(const float2* __restrict__ in, float2* __restrict__ out) {
    const int X = threadIdx.x;                    // 0..63 x-triple
    const int Y = blockIdx.x * 4 + threadIdx.y;   // 0..63 y-triple
    const int z = blockIdx.y;                     // 0..191 output z (block-uniform)
    const int b = blockIdx.z;

    const int k = z / 3, r = z - 3 * k;           // block-uniform (scalar)
    const int ix = 2 * X, iy = 2 * Y;
    const int xc = (ix + 2 < W) ? ix + 2 : W - 1;
    const int yc = (iy + 2 < H) ? iy + 2 : H - 1;

    const float2* base = in + (size_t)b * (D * H * W);

    float2 m[3][3];                               // z-merged 3x3 (y,x) patch
    if (r == 0) {
        const float2* p = base + (size_t)(2 * k) * (H * W);
        load_row3(p + (size_t)iy * W,       ix, xc, m[0]);
        load_row3(p + (size_t)(iy + 1) * W, ix, xc, m[1]);
        load_row3(p + (size_t)yc * W,       ix, xc, m[2]);
    } else {
        const int izA = (r == 1) ? 2 * k : 2 * k + 1;
        const int izB = (izA + 1 < D) ? izA + 1 : D - 1;
        const float wA = (r == 1) ? (1.0f / 3.0f) : (2.0f / 3.0f);
        const float wB = (r == 1) ? (2.0f / 3.0f) : (1.0f / 3.0f);
        const float2* pA = base + (size_t)izA * (H * W);
        const float2* pB = base + (size_t)izB * (H * W);
        float2 a[3][3], c[3][3];
        load_row3(pA + (size_t)iy * W,       ix, xc, a[0]);
        load_row3(pA + (size_t)(iy + 1) * W, ix, xc, a[1]);
        load_row3(pA + (size_t)yc * W,       ix, xc, a[2]);
        load_row3(pB + (size_t)iy * W,       ix, xc, c[0]);
        load_row3(pB + (size_t)(iy + 1) * W, ix, xc, c[1]);
        load_row3(pB + (size_t)yc * W,       ix, xc, c[2]);
#pragma unroll
        for (int i = 0; i < 3; ++i)
#pragma unroll
            for (int j = 0; j < 3; ++j) {
                m[i][j].x = wA * a[i][j].x + wB * c[i][j].x;
                m[i][j].y = wA * a[i][j].y + wB * c[i][j].y;
            }
    }

    // x-interp each row, then y-interp -> 3 output rows of 24 B/lane
    float2 t0[3], t1[3], t2[3];
    t0[0] = m[0][0]; t0[1] = lerp13(m[0][0], m[0][1]); t0[2] = lerp23(m[0][1], m[0][2]);
    t1[0] = m[1][0]; t1[1] = lerp13(m[1][0], m[1][1]); t1[2] = lerp23(m[1][1], m[1][2]);
    t2[0] = m[2][0]; t2[1] = lerp13(m[2][0], m[2][1]); t2[2] = lerp23(m[2][1], m[2][2]);

    float2* o0 = out + (((size_t)b * OD + z) * OH + 3 * Y) * OW + 3 * X;
    float2* o1 = o0 + OW;
    float2* o2 = o0 + 2 * OW;
    o0[0] = t0[0];                o0[1] = t0[1];                o0[2] = t0[2];
    o1[0] = lerp13(t0[0], t1[0]); o1[1] = lerp13(t0[1], t1[1]); o1[2] = lerp13(t0[2], t1[2]);
    o2[0] = lerp23(t1[0], t2[0]); o2[1] = lerp23(t1[1], t2[1]); o2[2] = lerp23(t1[2], t2[2]);
}

extern "C" void kernel_launch(void* const* d_in, const int* in_sizes, int n_in,
                              void* d_out, int out_size, void* d_ws, size_t ws_size,
                              hipStream_t stream) {
    const float2* in = (const float2*)d_in[0];
    float2* out = (float2*)d_out;
    dim3 block(64, 4, 1);
    dim3 grid(16, OD, B);    // (y-triple groups, output z, batch)
    resize9v<<<grid, block, 0, stream>>>(in, out);
}

// Round 7
// 27.988 us; speedup vs baseline: 1.2180x; 1.0106x over previous
//
#include <hip/hip_runtime.h>

// Resize [B,D,H,W,C=2] fp32, zoom 1.5/axis, neurite linear conv (edge clip).
// Per axis: out[3k]=in[2k], out[3k+1]=(in[2k]+2 in[2k+1])/3, out[3k+2]=(2 in[2k+1]+in[2k+2])/3.
// One thread = 1(z) x 3(y) x 3(x) output tile; weights are literals {1,1/3,2/3}.
// 1-D grid + XCD swizzle: each XCD owns a contiguous 48-z slab so every input
// z-plane is fetched into exactly one per-XCD L2 (T1, m192; bijective since 6144%8==0).
constexpr int B = 2, D = 128, H = 128, W = 128;
constexpr int OD = 192, OH = 192, OW = 192;

__device__ __forceinline__ float2 lerp13(float2 u, float2 v) {   // (u + 2v)/3
    constexpr float A = 1.0f / 3.0f, Bc = 2.0f / 3.0f;
    return float2{A * u.x + Bc * v.x, A * u.y + Bc * v.y};
}
__device__ __forceinline__ float2 lerp23(float2 u, float2 v) {   // (2u + v)/3
    constexpr float A = 1.0f / 3.0f, Bc = 2.0f / 3.0f;
    return float2{Bc * u.x + A * v.x, Bc * u.y + A * v.y};
}

__device__ __forceinline__ void load_row3(const float2* __restrict__ row,
                                          int ix, int xc, float2 out3[3]) {
    float4 q = *reinterpret_cast<const float4*>(row + ix);   // 16B aligned (ix even)
    out3[0] = float2{q.x, q.y};
    out3[1] = float2{q.z, q.w};
    out3[2] = row[xc];
}

__global__ __launch_bounds__(256)
void resize9x(const float2* __restrict__ in, float2* __restrict__ out) {
    // --- XCD z-locality swizzle (block-uniform, all scalar) ---
    const int bid   = blockIdx.x;          // 0..6143
    const int work  = (bid & 7) * 768 + (bid >> 3);
    const int xb    = work & 15;           // y-group 0..15
    const int zz    = work >> 4;           // 0..383
    const int b     = (zz >= 192) ? 1 : 0;
    const int z     = zz - b * 192;        // output z, contiguous per XCD chunk

    const int X = threadIdx.x;             // 0..63 x-triple
    const int Y = xb * 4 + threadIdx.y;    // 0..63 y-triple

    const int k = z / 3, r = z - 3 * k;    // block-uniform (scalar)
    const int ix = 2 * X, iy = 2 * Y;
    const int xc = (ix + 2 < W) ? ix + 2 : W - 1;
    const int yc = (iy + 2 < H) ? iy + 2 : H - 1;

    const float2* base = in + (size_t)b * (D * H * W);

    float2 m[3][3];                        // z-merged 3x3 (y,x) patch
    if (r == 0) {
        const float2* p = base + (size_t)(2 * k) * (H * W);
        load_row3(p + (size_t)iy * W,       ix, xc, m[0]);
        load_row3(p + (size_t)(iy + 1) * W, ix, xc, m[1]);
        load_row3(p + (size_t)yc * W,       ix, xc, m[2]);
    } else {
        const int izA = (r == 1) ? 2 * k : 2 * k + 1;
        const int izB = (izA + 1 < D) ? izA + 1 : D - 1;
        const float wA = (r == 1) ? (1.0f / 3.0f) : (2.0f / 3.0f);
        const float wB = (r == 1) ? (2.0f / 3.0f) : (1.0f / 3.0f);
        const float2* pA = base + (size_t)izA * (H * W);
        const float2* pB = base + (size_t)izB * (H * W);
        float2 a[3][3], c[3][3];
        load_row3(pA + (size_t)iy * W,       ix, xc, a[0]);
        load_row3(pA + (size_t)(iy + 1) * W, ix, xc, a[1]);
        load_row3(pA + (size_t)yc * W,       ix, xc, a[2]);
        load_row3(pB + (size_t)iy * W,       ix, xc, c[0]);
        load_row3(pB + (size_t)(iy + 1) * W, ix, xc, c[1]);
        load_row3(pB + (size_t)yc * W,       ix, xc, c[2]);
#pragma unroll
        for (int i = 0; i < 3; ++i)
#pragma unroll
            for (int j = 0; j < 3; ++j) {
                m[i][j].x = wA * a[i][j].x + wB * c[i][j].x;
                m[i][j].y = wA * a[i][j].y + wB * c[i][j].y;
            }
    }

    // x-interp each row, then y-interp -> 3 output rows of 24 B/lane
    float2 t0[3], t1[3], t2[3];
    t0[0] = m[0][0]; t0[1] = lerp13(m[0][0], m[0][1]); t0[2] = lerp23(m[0][1], m[0][2]);
    t1[0] = m[1][0]; t1[1] = lerp13(m[1][0], m[1][1]); t1[2] = lerp23(m[1][1], m[1][2]);
    t2[0] = m[2][0]; t2[1] = lerp13(m[2][0], m[2][1]); t2[2] = lerp23(m[2][1], m[2][2]);

    float2* o0 = out + (((size_t)b * OD + z) * OH + 3 * Y) * OW + 3 * X;
    float2* o1 = o0 + OW;
    float2* o2 = o0 + 2 * OW;
    o0[0] = t0[0];                o0[1] = t0[1];                o0[2] = t0[2];
    o1[0] = lerp13(t0[0], t1[0]); o1[1] = lerp13(t0[1], t1[1]); o1[2] = lerp13(t0[2], t1[2]);
    o2[0] = lerp23(t1[0], t2[0]); o2[1] = lerp23(t1[1], t2[1]); o2[2] = lerp23(t1[2], t2[2]);
}

extern "C" void kernel_launch(void* const* d_in, const int* in_sizes, int n_in,
                              void* d_out, int out_size, void* d_ws, size_t ws_size,
                              hipStream_t stream) {
    const float2* in = (const float2*)d_in[0];
    float2* out = (float2*)d_out;
    dim3 block(64, 4, 1);
    dim3 grid(16 * OD * B, 1, 1);   // 6144 blocks, swizzle-decoded in-kernel
    resize9x<<<grid, block, 0, stream>>>(in, out);
}